// Round 1
// baseline (727.141 us; speedup 1.0000x reference)
//
#include <hip/hip_runtime.h>

#define NEG_FILL -1.0e9f

using bf16x8 = __attribute__((ext_vector_type(8))) short;
using s16x4  = __attribute__((ext_vector_type(4))) short;
using f32x4  = __attribute__((ext_vector_type(4))) float;

// round-to-nearest-even fp32 -> bf16 (no NaNs in this data)
static __device__ __forceinline__ short f2bf(float f) {
    union { float f; unsigned u; } a; a.f = f;
    unsigned r = a.u + 0x7FFFu + ((a.u >> 16) & 1u);
    return (short)(r >> 16);
}

// ws layout:
// [0, 32768)        WT  bf16 [128][128]   WT[n][k] = (W1@W2)[k][n]
// [32768, 33280)    beff f32 [128]        b1@W2 + b2
// [33280, 164352)   pool f32-bits-as-int [256][128]

__global__ __launch_bounds__(256) void k_prep(
    const float* __restrict__ W1, const float* __restrict__ b1,
    const float* __restrict__ W2, const float* __restrict__ b2,
    short* __restrict__ WT, float* __restrict__ beff, int* __restrict__ pool)
{
    int blk = blockIdx.x, tid = threadIdx.x;
    if (blk < 128) {                      // pool init: 128*256 = 32768 entries
        pool[blk * 256 + tid] = __float_as_int(NEG_FILL);
        return;
    }
    if (blk < 192) {                      // Weff^T: 64 blocks * 256 = 16384 entries
        int e = (blk - 128) * 256 + tid;  // e = n*128 + k
        int n = e >> 7, k = e & 127;
        float s = 0.f;
        #pragma unroll 8
        for (int h = 0; h < 64; ++h) s = fmaf(W1[k * 64 + h], W2[h * 128 + n], s);
        WT[e] = f2bf(s);
    } else if (tid < 128) {               // beff
        float s = b2[tid];
        for (int h = 0; h < 64; ++h) s = fmaf(b1[h], W2[h * 128 + tid], s);
        beff[tid] = s;
    }
}

// Main fused kernel: one block = 64 rows of the flattened [B*N, 128] problem.
// GEMM via mfma_f32_16x16x32_bf16; epilogue does +beff, LayerNorm, ReLU,
// mask-fill, local-half store, and block-level max-pool -> global atomicMax.
__global__ __launch_bounds__(256) void k_main(
    const float* __restrict__ X, const int* __restrict__ mask,
    const short* __restrict__ WT, const float* __restrict__ beff,
    const float* __restrict__ gamma, const float* __restrict__ beta,
    float* __restrict__ out, int* __restrict__ pool)
{
    __shared__ short As[64][136];    // +8 shorts pad -> row stride 272B (4-bank shift)
    __shared__ short Ws[128][136];
    __shared__ int pool_s[128];

    const int tid = threadIdx.x;
    const int rowbase = blockIdx.x * 64;   // 64 rows, always within one b (2048%64==0)

    if (tid < 128) pool_s[tid] = __float_as_int(NEG_FILL);

    // stage Weff^T (bf16) into LDS: 2048 x 16B
    #pragma unroll
    for (int i = 0; i < 8; ++i) {
        int g = tid + i * 256;             // short8 id
        int n = g >> 4, koff = (g & 15) * 8;
        *(bf16x8*)&Ws[n][koff] = *(const bf16x8*)(WT + g * 8);
    }
    // stage X tile fp32 -> bf16: 2048 x float4
    #pragma unroll
    for (int i = 0; i < 8; ++i) {
        int f = tid + i * 256;
        int r = f >> 5, c4 = (f & 31) * 4;
        float4 xv = *(const float4*)(X + (size_t)(rowbase + r) * 128 + c4);
        s16x4 sv;
        sv[0] = f2bf(xv.x); sv[1] = f2bf(xv.y); sv[2] = f2bf(xv.z); sv[3] = f2bf(xv.w);
        *(s16x4*)&As[r][c4] = sv;
    }
    __syncthreads();

    const int wave = tid >> 6, lane = tid & 63;
    const int c = lane & 15, q = lane >> 4;

    f32x4 acc[8];
    const f32x4 zero = {0.f, 0.f, 0.f, 0.f};
    #pragma unroll
    for (int t = 0; t < 8; ++t) acc[t] = zero;

    // A frag: A[m=lane&15][k=q*8+j]; B frag: B[k=q*8+j][n=lane&15]
    const int arow = wave * 16 + c;
    #pragma unroll
    for (int kk = 0; kk < 4; ++kk) {
        bf16x8 a = *(const bf16x8*)&As[arow][kk * 32 + q * 8];
        #pragma unroll
        for (int t = 0; t < 8; ++t) {
            bf16x8 b = *(const bf16x8*)&Ws[t * 16 + c][kk * 32 + q * 8];
            acc[t] = __builtin_amdgcn_mfma_f32_16x16x32_bf16(a, b, acc[t], 0, 0, 0);
        }
    }

    // per-lane column params: col n = t*16 + c
    float be[8], ga[8], bt[8];
    #pragma unroll
    for (int t = 0; t < 8; ++t) {
        int n = t * 16 + c;
        be[t] = beff[n]; ga[t] = gamma[n]; bt[t] = beta[n];
    }

    // C/D layout: col = lane&15, row = q*4 + r
    float v[8][4];
    #pragma unroll
    for (int t = 0; t < 8; ++t)
        #pragma unroll
        for (int r = 0; r < 4; ++r) v[t][r] = acc[t][r] + be[t];

    #pragma unroll
    for (int r = 0; r < 4; ++r) {
        // row stats: 8 values per lane + 16 lanes of this quad hold the full row
        float s = 0.f, s2 = 0.f;
        #pragma unroll
        for (int t = 0; t < 8; ++t) { s += v[t][r]; s2 = fmaf(v[t][r], v[t][r], s2); }
        #pragma unroll
        for (int m = 1; m < 16; m <<= 1) {
            s  += __shfl_xor(s,  m, 64);
            s2 += __shfl_xor(s2, m, 64);
        }
        float mu  = s * (1.f / 128.f);
        float var = s2 * (1.f / 128.f) - mu * mu;
        float rs  = rsqrtf(var + 1e-3f);
        int rg = rowbase + wave * 16 + q * 4 + r;
        int mk = mask[rg];
        #pragma unroll
        for (int t = 0; t < 8; ++t) {
            float y = fmaf((v[t][r] - mu) * rs, ga[t], bt[t]);
            y = fmaxf(y, 0.f);
            y = mk ? y : NEG_FILL;
            v[t][r] = y;
            out[(size_t)rg * 256 + t * 16 + c] = y;
        }
    }

    // max-pool: values are >=0 or exactly -1e9, so int compare == float compare
    #pragma unroll
    for (int t = 0; t < 8; ++t) {
        float pm = fmaxf(fmaxf(v[t][0], v[t][1]), fmaxf(v[t][2], v[t][3]));
        pm = fmaxf(pm, __shfl_xor(pm, 16, 64));
        pm = fmaxf(pm, __shfl_xor(pm, 32, 64));
        if (q == 0) atomicMax(&pool_s[t * 16 + c], __float_as_int(pm));
    }
    __syncthreads();
    if (tid < 128) {
        int b = rowbase >> 11;             // 2048 rows per batch
        atomicMax(&pool[b * 128 + tid], pool_s[tid]);
    }
}

// broadcast pooled vector into out[:, :, 128:256]; 2^24 float4 writes
__global__ __launch_bounds__(256) void k_bcast(
    const float4* __restrict__ pool4, float4* __restrict__ out4)
{
    unsigned idx = blockIdx.x * 256 + threadIdx.x;
    unsigned row = idx >> 5;        // 32 float4 per row-half
    unsigned c4  = idx & 31;
    unsigned b   = row >> 11;
    out4[(size_t)row * 64 + 32 + c4] = pool4[b * 32 + c4];
}

extern "C" void kernel_launch(void* const* d_in, const int* in_sizes, int n_in,
                              void* d_out, int out_size, void* d_ws, size_t ws_size,
                              hipStream_t stream)
{
    const float* X     = (const float*)d_in[0];
    const int*   mask  = (const int*)d_in[1];
    const float* W1    = (const float*)d_in[2];
    const float* b1    = (const float*)d_in[3];
    const float* W2    = (const float*)d_in[4];
    const float* b2    = (const float*)d_in[5];
    const float* gamma = (const float*)d_in[6];
    const float* beta  = (const float*)d_in[7];
    float* out = (float*)d_out;

    short* WT   = (short*)d_ws;
    float* beff = (float*)((char*)d_ws + 32768);
    int*   pool = (int*)((char*)d_ws + 33280);

    k_prep<<<193, 256, 0, stream>>>(W1, b1, W2, b2, WT, beff, pool);
    k_main<<<8192, 256, 0, stream>>>(X, mask, WT, beff, gamma, beta, out, pool);
    k_bcast<<<65536, 256, 0, stream>>>((const float4*)pool, (float4*)out);
}

// Round 3
// 723.565 us; speedup vs baseline: 1.0049x; 1.0049x over previous
//
#include <hip/hip_runtime.h>
#include <hip/hip_bf16.h>

#define NEG_FILL -1.0e9f

using bf16x8 = __attribute__((ext_vector_type(8))) short;
using f32x4  = __attribute__((ext_vector_type(4))) float;   // native clang vector

// round-to-nearest-even fp32 -> bf16 (no NaNs in this data)
static __device__ __forceinline__ short f2bf(float f) {
    union { float f; unsigned u; } a; a.f = f;
    unsigned r = a.u + 0x7FFFu + ((a.u >> 16) & 1u);
    return (short)(r >> 16);
}

// pack 8 floats -> bf16x8 via packed cvt (v_cvt_pk_bf16_f32)
static __device__ __forceinline__ bf16x8 pack8(float4 a, float4 b) {
    union { __hip_bfloat162 h[4]; bf16x8 v; } u;
    u.h[0] = __float22bfloat162_rn({a.x, a.y});
    u.h[1] = __float22bfloat162_rn({a.z, a.w});
    u.h[2] = __float22bfloat162_rn({b.x, b.y});
    u.h[3] = __float22bfloat162_rn({b.z, b.w});
    return u.v;
}

// ws layout:
// [0, 32768)        WT  bf16 [128][128]   WT[n][k] = (W1@W2)[k][n]
// [32768, 33280)    beff f32 [128]        b1@W2 + b2
// [33280, 164352)   pool f32-bits-as-int [256][128]

__global__ __launch_bounds__(256) void k_prep(
    const float* __restrict__ W1, const float* __restrict__ b1,
    const float* __restrict__ W2, const float* __restrict__ b2,
    short* __restrict__ WT, float* __restrict__ beff, int* __restrict__ pool)
{
    int blk = blockIdx.x, tid = threadIdx.x;
    if (blk < 128) {                      // pool init: 128*256 = 32768 entries
        pool[blk * 256 + tid] = __float_as_int(NEG_FILL);
        return;
    }
    if (blk < 192) {                      // Weff^T: 64 blocks * 256 = 16384 entries
        int e = (blk - 128) * 256 + tid;  // e = n*128 + k
        int n = e >> 7, k = e & 127;
        float s = 0.f;
        #pragma unroll 8
        for (int h = 0; h < 64; ++h) s = fmaf(W1[k * 64 + h], W2[h * 128 + n], s);
        WT[e] = f2bf(s);
    } else if (tid < 128) {               // beff
        float s = b2[tid];
        for (int h = 0; h < 64; ++h) s = fmaf(b1[h], W2[h * 128 + tid], s);
        beff[tid] = s;
    }
}

// Main fused kernel: one block = 64 rows of the flattened [B*N, 128] problem.
// A-fragments loaded straight from global (X read exactly once, no reuse ->
// no LDS staging); Weff^T staged once in LDS. Epilogue: +beff, LayerNorm,
// ReLU, mask-fill, local-half store, block max-pool -> global atomicMax.
__global__ __launch_bounds__(256) void k_main(
    const float* __restrict__ X, const int* __restrict__ mask,
    const short* __restrict__ WT, const float* __restrict__ beff,
    const float* __restrict__ gamma, const float* __restrict__ beta,
    float* __restrict__ out, int* __restrict__ pool)
{
    __shared__ short Ws[128][136];   // +8 shorts pad
    __shared__ int pool_s[128];

    const int tid = threadIdx.x;
    const int rowbase = blockIdx.x * 64;   // 64 rows, always within one b (2048%64==0)

    if (tid < 128) pool_s[tid] = __float_as_int(NEG_FILL);

    // stage Weff^T (bf16) into LDS: 2048 x 16B
    #pragma unroll
    for (int i = 0; i < 8; ++i) {
        int g = tid + i * 256;             // short8 id
        int n = g >> 4, koff = (g & 15) * 8;
        *(bf16x8*)&Ws[n][koff] = *(const bf16x8*)(WT + g * 8);
    }

    const int wave = tid >> 6, lane = tid & 63;
    const int c = lane & 15, q = lane >> 4;
    const int rowloc = wave * 16 + c;              // A row this lane feeds
    const float* __restrict__ xrow = X + (size_t)(rowbase + rowloc) * 128;

    // per-lane column params (col n = t*16 + c); issue early, L1/L2-hot
    float be[8], ga[8], bt[8];
    #pragma unroll
    for (int t = 0; t < 8; ++t) {
        int n = t * 16 + c;
        be[t] = beff[n]; ga[t] = gamma[n]; bt[t] = beta[n];
    }

    __syncthreads();

    f32x4 acc[8];
    const f32x4 zero = {0.f, 0.f, 0.f, 0.f};
    #pragma unroll
    for (int t = 0; t < 8; ++t) acc[t] = zero;

    // A frag: A[m=lane&15][k=q*8+j] -> two float4 from global per K-step
    #pragma unroll
    for (int kk = 0; kk < 4; ++kk) {
        float4 x0 = *(const float4*)(xrow + kk * 32 + q * 8);
        float4 x1 = *(const float4*)(xrow + kk * 32 + q * 8 + 4);
        bf16x8 a = pack8(x0, x1);
        #pragma unroll
        for (int t = 0; t < 8; ++t) {
            bf16x8 b = *(const bf16x8*)&Ws[t * 16 + c][kk * 32 + q * 8];
            acc[t] = __builtin_amdgcn_mfma_f32_16x16x32_bf16(a, b, acc[t], 0, 0, 0);
        }
    }

    // C/D layout: col = lane&15, row = q*4 + r
    float v[8][4];
    #pragma unroll
    for (int t = 0; t < 8; ++t)
        #pragma unroll
        for (int r = 0; r < 4; ++r) v[t][r] = acc[t][r] + be[t];

    #pragma unroll
    for (int r = 0; r < 4; ++r) {
        float s = 0.f, s2 = 0.f;
        #pragma unroll
        for (int t = 0; t < 8; ++t) { s += v[t][r]; s2 = fmaf(v[t][r], v[t][r], s2); }
        #pragma unroll
        for (int m = 1; m < 16; m <<= 1) {
            s  += __shfl_xor(s,  m, 64);
            s2 += __shfl_xor(s2, m, 64);
        }
        float mu  = s * (1.f / 128.f);
        float var = s2 * (1.f / 128.f) - mu * mu;
        float rs  = rsqrtf(var + 1e-3f);
        int rg = rowbase + wave * 16 + q * 4 + r;
        int mk = mask[rg];
        #pragma unroll
        for (int t = 0; t < 8; ++t) {
            float y = fmaf((v[t][r] - mu) * rs, ga[t], bt[t]);
            y = fmaxf(y, 0.f);
            y = mk ? y : NEG_FILL;
            v[t][r] = y;
            out[(size_t)rg * 256 + t * 16 + c] = y;
        }
    }

    // max-pool: values are >=0 or exactly -1e9, so int compare == float compare
    #pragma unroll
    for (int t = 0; t < 8; ++t) {
        float pm = fmaxf(fmaxf(v[t][0], v[t][1]), fmaxf(v[t][2], v[t][3]));
        pm = fmaxf(pm, __shfl_xor(pm, 16, 64));
        pm = fmaxf(pm, __shfl_xor(pm, 32, 64));
        if (q == 0) atomicMax(&pool_s[t * 16 + c], __float_as_int(pm));
    }
    __syncthreads();
    if (tid < 128) {
        int b = rowbase >> 11;             // 2048 rows per batch
        atomicMax(&pool[b * 128 + tid], pool_s[tid]);
    }
}

// broadcast pooled vector into out[:, :, 128:256]
// grid-stride: 4096 blocks x 256 thr x 16 float4 = 16.7M float4 (256 MiB)
__global__ __launch_bounds__(256) void k_bcast(
    const f32x4* __restrict__ pool4, f32x4* __restrict__ out4)
{
    unsigned base = blockIdx.x * 256 + threadIdx.x;
    #pragma unroll
    for (int i = 0; i < 16; ++i) {
        unsigned idx = base + (unsigned)i * (4096u * 256u);
        unsigned row = idx >> 5;        // 32 float4 per row-half
        unsigned c4  = idx & 31;
        unsigned b   = row >> 11;
        f32x4 pv = pool4[b * 32 + c4];
        __builtin_nontemporal_store(pv, &out4[(size_t)row * 64 + 32 + c4]);
    }
}

extern "C" void kernel_launch(void* const* d_in, const int* in_sizes, int n_in,
                              void* d_out, int out_size, void* d_ws, size_t ws_size,
                              hipStream_t stream)
{
    const float* X     = (const float*)d_in[0];
    const int*   mask  = (const int*)d_in[1];
    const float* W1    = (const float*)d_in[2];
    const float* b1    = (const float*)d_in[3];
    const float* W2    = (const float*)d_in[4];
    const float* b2    = (const float*)d_in[5];
    const float* gamma = (const float*)d_in[6];
    const float* beta  = (const float*)d_in[7];
    float* out = (float*)d_out;

    short* WT   = (short*)d_ws;
    float* beff = (float*)((char*)d_ws + 32768);
    int*   pool = (int*)((char*)d_ws + 33280);

    k_prep<<<193, 256, 0, stream>>>(W1, b1, W2, b2, WT, beff, pool);
    k_main<<<8192, 256, 0, stream>>>(X, mask, WT, beff, gamma, beta, out, pool);
    k_bcast<<<4096, 256, 0, stream>>>((const f32x4*)pool, (f32x4*)out);
}